// Round 1
// baseline (2634.092 us; speedup 1.0000x reference)
//
#include <hip/hip_runtime.h>
#include <hip/hip_bf16.h>

// ---------- types ----------
typedef __attribute__((ext_vector_type(8))) short short8;   // 8 bf16 = 4 VGPRs (MFMA A/B frag)
typedef __attribute__((ext_vector_type(4))) short short4_t; // 4 bf16
typedef __attribute__((ext_vector_type(4))) float f32x4;    // MFMA C/D frag

__device__ __forceinline__ short f2bf(float x) {
  // round-to-nearest-even fp32 -> bf16
  unsigned int u = __builtin_bit_cast(unsigned int, x);
  unsigned int r = (u + 0x7fffu + ((u >> 16) & 1u)) >> 16;
  return (short)r;
}
__device__ __forceinline__ float bf2f(unsigned short u) {
  unsigned int i = ((unsigned int)u) << 16;
  return __builtin_bit_cast(float, i);
}

#define HDIM 512
#define NB   16    // batches per workgroup (MFMA N)
#define KT   16    // K-tiles of 32 (K = 512)
#define HROW 520   // shorts per h_lds row (1040 B: 512 data + pad -> bank spread, 16B aligned)

// ---------- kernel W: convert Wh fp32 -> bf16 ----------
__global__ __launch_bounds__(256) void kcvt(const float* __restrict__ Wh,
                                            short* __restrict__ Whb) {
  int i = blockIdx.x * 256 + threadIdx.x;          // 65536 float4 groups
  float4 v = ((const float4*)Wh)[i];
  short4_t o;
  o[0] = f2bf(v.x); o[1] = f2bf(v.y); o[2] = f2bf(v.z); o[3] = f2bf(v.w);
  ((short4_t*)Whb)[i] = o;
}

// ---------- kernel A: xproj[s][h][b] = sum_e emb[ids[b][s]][e]*Wi[h][e] + bi[h] + bh[h] (bf16) ----------
__global__ __launch_bounds__(256) void kxproj(const int* __restrict__ ids,    // [B=64][S=512]
                                              const float* __restrict__ emb,  // [V][256]
                                              const float* __restrict__ Wi,   // [512][256]
                                              const float* __restrict__ bi,   // [512]
                                              const float* __restrict__ bh,   // [512]
                                              short* __restrict__ xp) {       // [S][H][B] bf16
  const int s  = blockIdx.x;       // 0..511
  const int hb = blockIdx.y;       // 0..1  (h-block of 256)
  __shared__ float emb_t[32 * 68];   // [e][b], stride 68 floats (bank spread, 16B-aligned reads)
  __shared__ float wi_t[32 * 260];   // [e][h], stride 260 floats
  __shared__ int   ids_s[64];
  const int tid = threadIdx.x;
  const int b0 = (tid & 7) * 8;    // 8 batches per thread
  const int h0 = (tid >> 3) * 8;   // 8 h per thread (h-local 0..255)

  if (tid < 64) ids_s[tid] = ids[tid * 512 + s];
  __syncthreads();

  float acc[8][8];
  #pragma unroll
  for (int i = 0; i < 8; ++i)
    #pragma unroll
    for (int j = 0; j < 8; ++j) acc[i][j] = 0.f;

  for (int ec = 0; ec < 256; ec += 32) {
    // stage emb chunk [32e][64b] (transpose; coalesced 128B reads per emb row)
    #pragma unroll
    for (int j = 0; j < 8; ++j) {
      int idx = j * 256 + tid;
      int e = idx & 31, b = idx >> 5;
      emb_t[e * 68 + b] = emb[ids_s[b] * 256 + ec + e];
    }
    // stage Wi chunk [32e][256h] (transpose; coalesced float4 reads along e)
    #pragma unroll
    for (int j = 0; j < 8; ++j) {
      int idx4 = j * 256 + tid;
      int e4 = (idx4 & 7) * 4, hl = idx4 >> 3;
      float4 f = *(const float4*)&Wi[(hb * 256 + hl) * 256 + ec + e4];
      wi_t[(e4 + 0) * 260 + hl] = f.x;
      wi_t[(e4 + 1) * 260 + hl] = f.y;
      wi_t[(e4 + 2) * 260 + hl] = f.z;
      wi_t[(e4 + 3) * 260 + hl] = f.w;
    }
    __syncthreads();
    for (int e = 0; e < 32; ++e) {
      const float4 eb0 = *(const float4*)&emb_t[e * 68 + b0];
      const float4 eb1 = *(const float4*)&emb_t[e * 68 + b0 + 4];
      const float4 w0  = *(const float4*)&wi_t[e * 260 + h0];
      const float4 w1  = *(const float4*)&wi_t[e * 260 + h0 + 4];
      float av[8] = {eb0.x, eb0.y, eb0.z, eb0.w, eb1.x, eb1.y, eb1.z, eb1.w};
      float wv[8] = {w0.x, w0.y, w0.z, w0.w, w1.x, w1.y, w1.z, w1.w};
      #pragma unroll
      for (int i = 0; i < 8; ++i)
        #pragma unroll
        for (int j = 0; j < 8; ++j) acc[i][j] += av[i] * wv[j];
    }
    __syncthreads();
  }
  // epilogue: + (bi+bh), cvt bf16, store [s][h][b0..b0+8]
  #pragma unroll
  for (int hj = 0; hj < 8; ++hj) {
    int h = hb * 256 + h0 + hj;
    float add = bi[h] + bh[h];
    short8 pk;
    #pragma unroll
    for (int b2 = 0; b2 < 8; ++b2) pk[b2] = f2bf(acc[b2][hj] + add);
    *(short8*)&xp[(s * 512 + h) * 64 + b0] = pk;
  }
}

// ---------- kernel B: the recurrence. 4 WGs x 16 batches, sync-free. ----------
// Wave w (of 8) owns output rows [64w, 64w+64): 3 M-tiles (48 rows) as register-resident
// MFMA A-frags (192 VGPRs), 1 M-tile (16 rows) streamed from global bf16 Wh each step.
// h state (16 batches x 512, bf16) lives in LDS in B-frag-friendly [n][k] layout.
__global__ __launch_bounds__(512, 2) void krnn(const short* __restrict__ Whb, // [512][512] bf16
                                               const short* __restrict__ xp,  // [S][H][B] bf16
                                               float* __restrict__ d_out) {
  __shared__ short h_lds[NB * HROW];   // 16,640 B
  const int tid = threadIdx.x;
  const int w   = tid >> 6;       // wave 0..7
  const int l   = tid & 63;
  const int l15 = l & 15;
  const int q   = l >> 4;         // quad 0..3
  const int g   = blockIdx.x;     // batch group 0..3
  const int m_base = w * 64;

  // zero h state (h0 = 0)
  for (int i = tid; i < NB * HROW / 2; i += 512) ((int*)h_lds)[i] = 0;

  // load register-resident A-frags: A[m = l15][k = q*8 + j] per tile
  short8 areg[3][KT];
  #pragma unroll
  for (int t = 0; t < 3; ++t) {
    int m = m_base + t * 16 + l15;
    #pragma unroll
    for (int kt = 0; kt < KT; ++kt)
      areg[t][kt] = *(const short8*)&Whb[m * HDIM + kt * 32 + q * 8];
  }
  const short* a3base = &Whb[(m_base + 48 + l15) * HDIM + q * 8];
  __syncthreads();

  for (int s = 0; s < 512; ++s) {
    // prefetch x (bf16) for this step's epilogue; D rows: m = base + q*4 + i
    unsigned short xv[4][4];
    #pragma unroll
    for (int t = 0; t < 4; ++t)
      #pragma unroll
      for (int i = 0; i < 4; ++i) {
        int m = m_base + t * 16 + q * 4 + i;
        xv[t][i] = ((const unsigned short*)xp)[(s * HDIM + m) * 64 + g * NB + l15];
      }

    f32x4 acc0 = {0.f, 0.f, 0.f, 0.f}, acc1 = acc0, acc2 = acc0, acc3 = acc0;
    #pragma unroll
    for (int kt = 0; kt < KT; ++kt) {
      // B-frag: B[k][n] = h[n][k], n = l15, k = kt*32 + q*8 + j
      short8 bfrag = *(const short8*)&h_lds[l15 * HROW + kt * 32 + q * 8];
      short8 a3    = *(const short8*)&a3base[kt * 32];
      acc0 = __builtin_amdgcn_mfma_f32_16x16x32_bf16(areg[0][kt], bfrag, acc0, 0, 0, 0);
      acc1 = __builtin_amdgcn_mfma_f32_16x16x32_bf16(areg[1][kt], bfrag, acc1, 0, 0, 0);
      acc2 = __builtin_amdgcn_mfma_f32_16x16x32_bf16(areg[2][kt], bfrag, acc2, 0, 0, 0);
      acc3 = __builtin_amdgcn_mfma_f32_16x16x32_bf16(a3,          bfrag, acc3, 0, 0, 0);
    }
    __syncthreads();   // all waves done reading h_lds

    // epilogue: z = Wh.h + (x + bh), h' = sigmoid(z); write back in [n][k] layout
    #pragma unroll
    for (int t = 0; t < 4; ++t) {
      f32x4 a = (t == 0) ? acc0 : (t == 1) ? acc1 : (t == 2) ? acc2 : acc3;
      short4_t hh;
      #pragma unroll
      for (int i = 0; i < 4; ++i) {
        float z = a[i] + bf2f(xv[t][i]);
        float hv = 1.f / (1.f + __expf(-z));
        hh[i] = f2bf(hv);
        if (s == 511) {  // final hidden (fp32) -> d_out
          int m = m_base + t * 16 + q * 4 + i;
          d_out[64 + (g * NB + l15) * HDIM + m] = hv;
        }
      }
      int row0 = m_base + t * 16 + q * 4;  // 4 consecutive k -> one ds_write_b64
      *(short4_t*)&h_lds[l15 * HROW + row0] = hh;
    }
    __syncthreads();   // h' visible before next step's reads
  }
}

// ---------- kernel C: sig[b] = sigmoid(hidden[b] . Wf + bf) ----------
__global__ __launch_bounds__(256) void kfin(const float* __restrict__ hid,  // d_out+64, [64][512]
                                            const float* __restrict__ Wf,   // [512]
                                            const float* __restrict__ bfp,  // [1]
                                            float* __restrict__ out) {
  __shared__ float red[4][64];
  int t = threadIdx.x, b = t & 63, qq = t >> 6;
  const float4* hv = (const float4*)&hid[b * 512 + qq * 128];
  const float4* wv = (const float4*)&Wf[qq * 128];
  float p = 0.f;
  #pragma unroll 8
  for (int k = 0; k < 32; ++k) {
    float4 hx = hv[k]; float4 wx = wv[k];
    p += hx.x * wx.x + hx.y * wx.y + hx.z * wx.z + hx.w * wx.w;
  }
  red[qq][b] = p;
  __syncthreads();
  if (t < 64) {
    float z = red[0][t] + red[1][t] + red[2][t] + red[3][t] + bfp[0];
    out[t] = 1.f / (1.f + __expf(-z));
  }
}

extern "C" void kernel_launch(void* const* d_in, const int* in_sizes, int n_in,
                              void* d_out, int out_size, void* d_ws, size_t ws_size,
                              hipStream_t stream) {
  const int*   ids = (const int*)d_in[0];
  const float* emb = (const float*)d_in[1];
  const float* Wh  = (const float*)d_in[2];
  const float* bh  = (const float*)d_in[3];
  const float* Wi  = (const float*)d_in[4];
  const float* bi  = (const float*)d_in[5];
  const float* Wf  = (const float*)d_in[6];
  const float* bf_ = (const float*)d_in[7];
  float* out = (float*)d_out;

  short* xp  = (short*)d_ws;                              // [512][512][64] bf16 = 32 MiB
  short* Whb = (short*)((char*)d_ws + (size_t)33554432);  // [512][512] bf16 = 512 KiB
  (void)in_sizes; (void)n_in; (void)out_size; (void)ws_size;

  kcvt  <<<256, 256, 0, stream>>>(Wh, Whb);
  kxproj<<<dim3(512, 2), 256, 0, stream>>>(ids, emb, Wi, bi, bh, xp);
  krnn  <<<4, 512, 0, stream>>>(Whb, xp, out);
  kfin  <<<1, 256, 0, stream>>>(out + 64, Wf, bf_, out);
}